// Round 1
// baseline (5555.070 us; speedup 1.0000x reference)
//
#include <hip/hip_runtime.h>

#define D 128

// out[i] = b[i % 128]
__global__ void init_out_kernel(float* __restrict__ out, const float* __restrict__ b, int total) {
    int idx = blockIdx.x * blockDim.x + threadIdx.x;
    if (idx < total) out[idx] = b[idx & (D - 1)];
}

// y = x @ W.T   (y[r][col] = sum_k x[r][k] * W[col][k])
__global__ __launch_bounds__(256) void gemm_xwT_kernel(const float* __restrict__ x,
                                                       const float* __restrict__ W,
                                                       float* __restrict__ y,
                                                       int n_rows) {
    // W tile in LDS, padded +1 to avoid bank conflicts (addr = col*129 + k)
    __shared__ float Wl[D][D + 1];   // 66048 B
    __shared__ float Xl[8][D];       //  4096 B
    for (int i = threadIdx.x; i < D * D; i += 256) {
        Wl[i >> 7][i & (D - 1)] = W[i];
    }
    int row0 = blockIdx.x * 8;
    for (int i = threadIdx.x; i < 8 * D; i += 256) {
        int rr = i >> 7;
        int k  = i & (D - 1);
        int r  = row0 + rr;
        Xl[rr][k] = (r < n_rows) ? x[(size_t)r * D + k] : 0.0f;
    }
    __syncthreads();

    int col   = threadIdx.x & (D - 1);
    int rhalf = threadIdx.x >> 7;  // 0 or 1
    for (int rr = rhalf; rr < 8; rr += 2) {
        int r = row0 + rr;
        if (r >= n_rows) continue;
        float acc = 0.0f;
#pragma unroll 16
        for (int k = 0; k < D; ++k) {
            acc += Xl[rr][k] * Wl[col][k];
        }
        y[(size_t)r * D + col] = acc;
    }
}

// For each edge (r, c, v): out[r][:] += v * y[c][:]
// 32 threads per edge, float4 per thread (32*4 = 128 floats).
__global__ __launch_bounds__(256) void scatter_kernel(const int* __restrict__ rows,
                                                      const int* __restrict__ cols,
                                                      const float* __restrict__ vals,
                                                      const float* __restrict__ y,
                                                      float* __restrict__ out,
                                                      long long n_work) {
    long long idx = (long long)blockIdx.x * blockDim.x + threadIdx.x;
    if (idx >= n_work) return;
    int e    = (int)(idx >> 5);
    int lane = (int)(idx & 31);
    int r = rows[e];
    int c = cols[e];
    float v = vals[e];
    const float4 src = *(const float4*)(y + (size_t)c * D + lane * 4);
    float* dst = out + (size_t)r * D + lane * 4;
    atomicAdd(dst + 0, v * src.x);
    atomicAdd(dst + 1, v * src.y);
    atomicAdd(dst + 2, v * src.z);
    atomicAdd(dst + 3, v * src.w);
}

extern "C" void kernel_launch(void* const* d_in, const int* in_sizes, int n_in,
                              void* d_out, int out_size, void* d_ws, size_t ws_size,
                              hipStream_t stream) {
    const float* x    = (const float*)d_in[0];
    const int*   erow = (const int*)d_in[1];
    const int*   ecol = (const int*)d_in[2];
    const float* eval_= (const float*)d_in[3];
    const float* W    = (const float*)d_in[4];
    const float* b    = (const float*)d_in[5];
    float* out = (float*)d_out;
    float* y   = (float*)d_ws;  // n_nodes * 128 floats = 51.2 MB

    int n_nodes  = in_sizes[0] / D;
    int n_edges  = in_sizes[1];
    int total_out = n_nodes * D;

    // 1) out = broadcast(b)
    init_out_kernel<<<(total_out + 255) / 256, 256, 0, stream>>>(out, b, total_out);

    // 2) y = x @ W.T
    gemm_xwT_kernel<<<(n_nodes + 7) / 8, 256, 0, stream>>>(x, W, y, n_nodes);

    // 3) out[r] += v * y[c]  (atomics)
    long long n_work = (long long)n_edges * 32;
    int blocks = (int)((n_work + 255) / 256);
    scatter_kernel<<<blocks, 256, 0, stream>>>(erow, ecol, eval_, y, out, n_work);
}

// Round 2
// 1041.812 us; speedup vs baseline: 5.3321x; 5.3321x over previous
//
#include <hip/hip_runtime.h>

#define D 128

// y = x @ W.T   (y[r][col] = sum_k x[r][k] * W[col][k])
__global__ __launch_bounds__(256) void gemm_xwT_kernel(const float* __restrict__ x,
                                                       const float* __restrict__ W,
                                                       float* __restrict__ y,
                                                       int n_rows) {
    __shared__ float Wl[D][D + 1];
    __shared__ float Xl[8][D];
    for (int i = threadIdx.x; i < D * D; i += 256) {
        Wl[i >> 7][i & (D - 1)] = W[i];
    }
    int row0 = blockIdx.x * 8;
    for (int i = threadIdx.x; i < 8 * D; i += 256) {
        int rr = i >> 7;
        int k  = i & (D - 1);
        int r  = row0 + rr;
        Xl[rr][k] = (r < n_rows) ? x[(size_t)r * D + k] : 0.0f;
    }
    __syncthreads();

    int col   = threadIdx.x & (D - 1);
    int rhalf = threadIdx.x >> 7;
    for (int rr = rhalf; rr < 8; rr += 2) {
        int r = row0 + rr;
        if (r >= n_rows) continue;
        float acc = 0.0f;
#pragma unroll 16
        for (int k = 0; k < D; ++k) {
            acc += Xl[rr][k] * Wl[col][k];
        }
        y[(size_t)r * D + col] = acc;
    }
}

__global__ void zero_int_kernel(int* __restrict__ p, int n) {
    int i = blockIdx.x * blockDim.x + threadIdx.x;
    if (i < n) p[i] = 0;
}

__global__ void hist_kernel(const int* __restrict__ rows, int* __restrict__ deg, int n_edges) {
    int e = blockIdx.x * blockDim.x + threadIdx.x;
    if (e < n_edges) atomicAdd(&deg[rows[e]], 1);
}

// Single-block exclusive scan of deg[0..n) -> offsets[0..n], cursor[i]=offsets[i]
__global__ __launch_bounds__(1024) void scan_kernel(const int* __restrict__ deg,
                                                    int* __restrict__ offsets,
                                                    int* __restrict__ cursor,
                                                    int n) {
    __shared__ int sums[1024];
    int t = threadIdx.x;
    int chunk = (n + 1023) / 1024;
    int beg = t * chunk;
    int end = min(n, beg + chunk);
    int s = 0;
    for (int i = beg; i < end; ++i) s += deg[i];
    sums[t] = s;
    __syncthreads();
    // inclusive Hillis-Steele scan over 1024 partials
    for (int off = 1; off < 1024; off <<= 1) {
        int v = (t >= off) ? sums[t - off] : 0;
        __syncthreads();
        sums[t] += v;
        __syncthreads();
    }
    int run = (t == 0) ? 0 : sums[t - 1];  // exclusive prefix of this chunk
    for (int i = beg; i < end; ++i) {
        int d = deg[i];
        offsets[i] = run;
        cursor[i]  = run;
        run += d;
    }
    if (t == 1023) offsets[n] = sums[1023];
}

__global__ void fill_kernel(const int* __restrict__ rows, const int* __restrict__ cols,
                            const float* __restrict__ vals,
                            int* __restrict__ cursor,
                            int* __restrict__ csr_col, float* __restrict__ csr_val,
                            int n_edges) {
    int e = blockIdx.x * blockDim.x + threadIdx.x;
    if (e >= n_edges) return;
    int r = rows[e];
    int pos = atomicAdd(&cursor[r], 1);
    csr_col[pos] = cols[e];
    csr_val[pos] = vals[e];
}

// One wave (64 lanes) per node: out[r][:] = b[:] + sum_{j in row r} v_j * y[c_j][:]
__global__ __launch_bounds__(256) void gather_kernel(const int* __restrict__ offsets,
                                                     const int* __restrict__ csr_col,
                                                     const float* __restrict__ csr_val,
                                                     const float* __restrict__ y,
                                                     const float* __restrict__ b,
                                                     float* __restrict__ out,
                                                     int n_nodes) {
    int gwave = (int)((blockIdx.x * (long long)blockDim.x + threadIdx.x) >> 6);
    int lane = threadIdx.x & 63;
    if (gwave >= n_nodes) return;
    int beg = offsets[gwave];
    int end = offsets[gwave + 1];
    float a0 = 0.0f, a1 = 0.0f;
    int j = beg;
    for (; j + 1 < end; j += 2) {
        int c0 = csr_col[j];
        int c1 = csr_col[j + 1];
        float v0 = csr_val[j];
        float v1 = csr_val[j + 1];
        float2 s0 = *(const float2*)(y + (size_t)c0 * D + lane * 2);
        float2 s1 = *(const float2*)(y + (size_t)c1 * D + lane * 2);
        a0 += v0 * s0.x + v1 * s1.x;
        a1 += v0 * s0.y + v1 * s1.y;
    }
    if (j < end) {
        int c = csr_col[j];
        float v = csr_val[j];
        float2 s = *(const float2*)(y + (size_t)c * D + lane * 2);
        a0 += v * s.x;
        a1 += v * s.y;
    }
    float2 bb = *(const float2*)(b + lane * 2);
    float2 o;
    o.x = a0 + bb.x;
    o.y = a1 + bb.y;
    *(float2*)(out + (size_t)gwave * D + lane * 2) = o;
}

extern "C" void kernel_launch(void* const* d_in, const int* in_sizes, int n_in,
                              void* d_out, int out_size, void* d_ws, size_t ws_size,
                              hipStream_t stream) {
    const float* x    = (const float*)d_in[0];
    const int*   erow = (const int*)d_in[1];
    const int*   ecol = (const int*)d_in[2];
    const float* eval_= (const float*)d_in[3];
    const float* W    = (const float*)d_in[4];
    const float* b    = (const float*)d_in[5];
    float* out = (float*)d_out;

    int n_nodes = in_sizes[0] / D;
    int n_edges = in_sizes[1];

    // Workspace layout (bytes):
    char* ws = (char*)d_ws;
    float* y       = (float*)ws;                          // n_nodes*D*4   = 51.2 MB
    ws += (size_t)n_nodes * D * sizeof(float);
    int* deg       = (int*)ws;  ws += (size_t)n_nodes * sizeof(int);        // 0.4 MB
    int* offsets   = (int*)ws;  ws += ((size_t)n_nodes + 1) * sizeof(int);  // 0.4 MB
    int* cursor    = (int*)ws;  ws += (size_t)n_nodes * sizeof(int);        // 0.4 MB
    int* csr_col   = (int*)ws;  ws += (size_t)n_edges * sizeof(int);        // 12.8 MB
    float* csr_val = (float*)ws;                                            // 12.8 MB

    // 1) y = x @ W.T
    gemm_xwT_kernel<<<(n_nodes + 7) / 8, 256, 0, stream>>>(x, W, y, n_nodes);

    // 2) CSR build: histogram -> scan -> fill
    zero_int_kernel<<<(n_nodes + 255) / 256, 256, 0, stream>>>(deg, n_nodes);
    hist_kernel<<<(n_edges + 255) / 256, 256, 0, stream>>>(erow, deg, n_edges);
    scan_kernel<<<1, 1024, 0, stream>>>(deg, offsets, cursor, n_nodes);
    fill_kernel<<<(n_edges + 255) / 256, 256, 0, stream>>>(erow, ecol, eval_, cursor,
                                                           csr_col, csr_val, n_edges);

    // 3) gather: out[r] = b + sum v * y[c]
    long long n_thr = (long long)n_nodes * 64;
    int blocks = (int)((n_thr + 255) / 256);
    gather_kernel<<<blocks, 256, 0, stream>>>(offsets, csr_col, csr_val, y, b, out, n_nodes);
}

// Round 3
// 902.420 us; speedup vs baseline: 6.1557x; 1.1545x over previous
//
#include <hip/hip_runtime.h>

#define D 128

typedef unsigned short u16;

__device__ inline u16 f32_to_bf16(float f) {
    unsigned int u = __float_as_uint(f);
    u += 0x7fffu + ((u >> 16) & 1u);  // round-to-nearest-even
    return (u16)(u >> 16);
}

// y_bf16 = bf16(x @ W.T)
// 128x128 tile per block, 256 threads, 8x8 register blocking.
__global__ __launch_bounds__(256) void gemm_kernel(const float* __restrict__ x,
                                                   const float* __restrict__ W,
                                                   u16* __restrict__ y,
                                                   int n_rows) {
    __shared__ float Wt[128 * 128];  // Wt[k*128 + c] = W[c*128 + k]
    __shared__ float Xt[128 * 128];  // Xt[k*128 + r] = x[(row0+r)*128 + k]
    const int t = threadIdx.x;
    const int row0 = blockIdx.x * 128;

    // LDS-linear writes (conflict-free); strided global reads.
    // W (64 KB) is L2/L3-hot across blocks; x tile lines stay in L1 across k-reuse.
    for (int e = t; e < 128 * 128; e += 256) {
        int k = e >> 7, c = e & 127;
        Wt[e] = W[c * 128 + k];
    }
    for (int e = t; e < 128 * 128; e += 256) {
        int k = e >> 7, r = e & 127;
        int row = row0 + r;
        Xt[e] = (row < n_rows) ? x[(size_t)row * 128 + k] : 0.0f;
    }
    __syncthreads();

    const int cg = (t & 15) * 4;  // col base: cols cg..cg+3 and cg+64..cg+67
    const int rg = (t >> 4) * 4;  // row base: rows rg..rg+3 and rg+64..rg+67

    float acc[8][8];
#pragma unroll
    for (int i = 0; i < 8; ++i)
#pragma unroll
        for (int j = 0; j < 8; ++j) acc[i][j] = 0.0f;

    for (int k = 0; k < 128; ++k) {
        const float4 w0 = *(const float4*)&Wt[k * 128 + cg];
        const float4 w1 = *(const float4*)&Wt[k * 128 + 64 + cg];
        const float4 x0 = *(const float4*)&Xt[k * 128 + rg];
        const float4 x1 = *(const float4*)&Xt[k * 128 + 64 + rg];
        const float xs[8] = {x0.x, x0.y, x0.z, x0.w, x1.x, x1.y, x1.z, x1.w};
        const float ws[8] = {w0.x, w0.y, w0.z, w0.w, w1.x, w1.y, w1.z, w1.w};
#pragma unroll
        for (int i = 0; i < 8; ++i)
#pragma unroll
            for (int j = 0; j < 8; ++j) acc[i][j] += xs[i] * ws[j];
    }

#pragma unroll
    for (int i = 0; i < 8; ++i) {
        int row = row0 + rg + (i & 3) + (i >> 2) * 64;
        if (row >= n_rows) continue;
#pragma unroll
        for (int jh = 0; jh < 2; ++jh) {
            ushort4 p;
            p.x = f32_to_bf16(acc[i][jh * 4 + 0]);
            p.y = f32_to_bf16(acc[i][jh * 4 + 1]);
            p.z = f32_to_bf16(acc[i][jh * 4 + 2]);
            p.w = f32_to_bf16(acc[i][jh * 4 + 3]);
            *(ushort4*)(y + (size_t)row * D + cg + jh * 64) = p;
        }
    }
}

__global__ void zero_int_kernel(int* __restrict__ p, int n) {
    int i = blockIdx.x * blockDim.x + threadIdx.x;
    if (i < n) p[i] = 0;
}

__global__ void hist_kernel(const int* __restrict__ rows, int* __restrict__ deg, int n_edges) {
    int e = blockIdx.x * blockDim.x + threadIdx.x;
    if (e < n_edges) atomicAdd(&deg[rows[e]], 1);
}

// Single-block exclusive scan: deg[0..n) -> offsets[0..n], cursor[i]=offsets[i]
__global__ __launch_bounds__(1024) void scan_kernel(const int* __restrict__ deg,
                                                    int* __restrict__ offsets,
                                                    int* __restrict__ cursor,
                                                    int n) {
    __shared__ int sums[1024];
    int t = threadIdx.x;
    int chunk = (n + 1023) / 1024;
    int beg = t * chunk;
    int end = min(n, beg + chunk);
    int s = 0;
    for (int i = beg; i < end; ++i) s += deg[i];
    sums[t] = s;
    __syncthreads();
    for (int off = 1; off < 1024; off <<= 1) {
        int v = (t >= off) ? sums[t - off] : 0;
        __syncthreads();
        sums[t] += v;
        __syncthreads();
    }
    int run = (t == 0) ? 0 : sums[t - 1];
    for (int i = beg; i < end; ++i) {
        int d = deg[i];
        offsets[i] = run;
        cursor[i]  = run;
        run += d;
    }
    if (t == 1023) offsets[n] = sums[1023];
}

// One packed 8B store per edge (halves line touches vs two 4B stores).
__global__ void fill_kernel(const int* __restrict__ rows, const int* __restrict__ cols,
                            const float* __restrict__ vals,
                            int* __restrict__ cursor,
                            int2* __restrict__ csr, int n_edges) {
    int e = blockIdx.x * blockDim.x + threadIdx.x;
    if (e >= n_edges) return;
    int r = rows[e];
    int pos = atomicAdd(&cursor[r], 1);
    csr[pos] = make_int2(cols[e], __float_as_int(vals[e]));
}

// One wave per node: out[r][:] = b[:] + sum_j v_j * y_bf16[c_j][:]
__global__ __launch_bounds__(256) void gather_kernel(const int* __restrict__ offsets,
                                                     const int2* __restrict__ csr,
                                                     const u16* __restrict__ y,
                                                     const float* __restrict__ b,
                                                     float* __restrict__ out,
                                                     int n_nodes) {
    int w = (int)(((long long)blockIdx.x * blockDim.x + threadIdx.x) >> 6);
    int lane = threadIdx.x & 63;
    if (w >= n_nodes) return;
    int beg = offsets[w];
    int end = offsets[w + 1];
    float a0 = 0.0f, a1 = 0.0f;
    int j = beg;
    for (; j + 1 < end; j += 2) {
        int2 e0 = csr[j];
        int2 e1 = csr[j + 1];
        unsigned int p0 = *(const unsigned int*)(y + (size_t)e0.x * D + lane * 2);
        unsigned int p1 = *(const unsigned int*)(y + (size_t)e1.x * D + lane * 2);
        float v0 = __int_as_float(e0.y);
        float v1 = __int_as_float(e1.y);
        a0 += v0 * __uint_as_float(p0 << 16) + v1 * __uint_as_float(p1 << 16);
        a1 += v0 * __uint_as_float(p0 & 0xffff0000u) + v1 * __uint_as_float(p1 & 0xffff0000u);
    }
    if (j < end) {
        int2 e0 = csr[j];
        unsigned int p0 = *(const unsigned int*)(y + (size_t)e0.x * D + lane * 2);
        float v0 = __int_as_float(e0.y);
        a0 += v0 * __uint_as_float(p0 << 16);
        a1 += v0 * __uint_as_float(p0 & 0xffff0000u);
    }
    float2 bb = *(const float2*)(b + lane * 2);
    float2 o;
    o.x = a0 + bb.x;
    o.y = a1 + bb.y;
    *(float2*)(out + (size_t)w * D + lane * 2) = o;
}

extern "C" void kernel_launch(void* const* d_in, const int* in_sizes, int n_in,
                              void* d_out, int out_size, void* d_ws, size_t ws_size,
                              hipStream_t stream) {
    const float* x    = (const float*)d_in[0];
    const int*   erow = (const int*)d_in[1];
    const int*   ecol = (const int*)d_in[2];
    const float* eval_= (const float*)d_in[3];
    const float* W    = (const float*)d_in[4];
    const float* b    = (const float*)d_in[5];
    float* out = (float*)d_out;

    int n_nodes = in_sizes[0] / D;
    int n_edges = in_sizes[1];

    // Workspace layout
    char* ws = (char*)d_ws;
    u16* y = (u16*)ws;           ws += (size_t)n_nodes * D * sizeof(u16);   // 25.6 MB
    int2* csr = (int2*)ws;       ws += (size_t)n_edges * sizeof(int2);      // 25.6 MB
    int* deg = (int*)ws;         ws += (size_t)n_nodes * sizeof(int);
    int* offsets = (int*)ws;     ws += ((size_t)n_nodes + 1) * sizeof(int);
    int* cursor = (int*)ws;

    // 1) y = bf16(x @ W.T)
    gemm_kernel<<<(n_nodes + 127) / 128, 256, 0, stream>>>(x, W, y, n_nodes);

    // 2) CSR build
    zero_int_kernel<<<(n_nodes + 255) / 256, 256, 0, stream>>>(deg, n_nodes);
    hist_kernel<<<(n_edges + 255) / 256, 256, 0, stream>>>(erow, deg, n_edges);
    scan_kernel<<<1, 1024, 0, stream>>>(deg, offsets, cursor, n_nodes);
    fill_kernel<<<(n_edges + 255) / 256, 256, 0, stream>>>(erow, ecol, eval_, cursor, csr, n_edges);

    // 3) gather
    long long n_thr = (long long)n_nodes * 64;
    gather_kernel<<<(int)((n_thr + 255) / 256), 256, 0, stream>>>(offsets, csr, y, b, out, n_nodes);
}